// Round 11
// baseline (119.829 us; speedup 1.0000x reference)
//
#include <hip/hip_runtime.h>
#include <cstddef>

#define B_    4
#define CIN_  256
#define COUT_ 256
#define H_    64
#define W_    64
#define KK_   9
#define G_    4
#define NSL   36          // 36 K=64 steps
#define PW    80          // padded row width  (pad 8 each side)
#define PH    80          // padded rows
#define PADO  8           // pad offset

typedef short bf16x8 __attribute__((ext_vector_type(8)));
typedef float f32x4  __attribute__((ext_vector_type(4)));
typedef __attribute__((address_space(1))) const unsigned int* gptr_t;
typedef __attribute__((address_space(3))) unsigned int*       lptr_t;

__device__ __forceinline__ unsigned short f2bf(float v) {
    unsigned int u = __float_as_uint(v);
    u += 0x7fffu + ((u >> 16) & 1u);
    return (unsigned short)(u >> 16);
}
__device__ __forceinline__ float f_lo(unsigned int u) { return __uint_as_float(u << 16); }
__device__ __forceinline__ float f_hi(unsigned int u) { return __uint_as_float(u & 0xffff0000u); }

// Merged prep (r7 verbatim):
//   blocks [0,512):    xTp interior rows (x-borders zeroed inline)
//   blocks [512,576):  xTp border rows zero-fill
//   blocks [576,2880): wb weight repack (36 tiles, pos-swizzled)
__global__ __launch_bounds__(256) void prep_kernel(const float* __restrict__ x,
                                                   unsigned short* __restrict__ xTp,
                                                   const float* __restrict__ w,
                                                   unsigned short* __restrict__ wb) {
    const int tid = threadIdx.x;
    if (blockIdx.x < 512) {
        __shared__ unsigned short s[128][66];
        const int bh    = blockIdx.x >> 1;
        const int chalf = blockIdx.x & 1;
        const int b     = bh >> 6, h = bh & 63;
        const size_t src_base = ((size_t)b * CIN_ + chalf * 128) * (H_ * W_) + h * W_;
        #pragma unroll 4
        for (int k = 0; k < 32; ++k) {
            int i = k * 256 + tid;
            int c = i >> 6, ww = i & 63;
            s[c][ww] = f2bf(x[src_base + (size_t)c * (H_ * W_) + ww]);
        }
        __syncthreads();
        const size_t dst_row = ((size_t)b * PH + (h + PADO)) * PW;
        #pragma unroll 4
        for (int k = 0; k < 20; ++k) {              // 80 w' x 64 ch-pairs
            int j  = k * 256 + tid;
            int c2 = (j & 63) * 2, wp = j >> 6;     // wp in [0,80)
            unsigned int v = 0;
            if (wp >= PADO && wp < PADO + W_) {
                int ww = wp - PADO;
                v = (unsigned int)s[c2][ww] | ((unsigned int)s[c2 + 1][ww] << 16);
            }
            *(unsigned int*)(xTp + (dst_row + wp) * 256 + chalf * 128 + c2) = v;
        }
    } else if (blockIdx.x < 576) {
        const int bidx = blockIdx.x - 512;          // [0,64)
        const int b = bidx >> 4, rr = bidx & 15;
        const int yp = (rr < PADO) ? rr : (PH - 16 + rr);   // 0..7 or 72..79
        unsigned short* dst = xTp + ((size_t)b * PH + yp) * PW * 256;
        #pragma unroll
        for (int k = 0; k < 10; ++k) {              // 80*256 shorts = 2560 x 16B
            *(uint4*)(dst + (size_t)(k * 256 + tid) * 8) = make_uint4(0, 0, 0, 0);
        }
    } else {
        int idx = (blockIdx.x - 576) * 256 + tid;   // 36*16384 exactly
        int e   = idx & 7;
        int pos = (idx >> 3) & 7;
        int o   = (idx >> 6) & 255;
        int t   = idx >> 14;                        // g*9 + kk
        int g   = t / 9, kk = t - g * 9;
        int j   = pos ^ (o & 7);
        int c   = g * 64 + j * 8 + e;
        wb[idx] = f2bf(w[(o * CIN_ + c) * KK_ + kk]);
    }
}

// Main kernel: 512 blocks x 512 threads, 2 blocks/CU (48 KB LDS each) =
// 4 waves/SIMD in TWO INDEPENDENT barrier domains -- the untested TLP
// quadrant. Block = (b, h, ohalf): 128 outs x 64 px, full K (36 steps).
// Wave = 32 outs x 32 px. W-DMA not duplicated (each block its own half);
// sampling duplicated 2x (VALU has headroom; r3 precedent). Unpinned
// schedule (r10: compiler = hand-pinned), one __syncthreads per step.
__global__ __launch_bounds__(512, 4) void dcn_kernel(
    const unsigned short* __restrict__ xTp, const float* __restrict__ y,
    const float* __restrict__ w_off, const unsigned short* __restrict__ wb,
    float* __restrict__ out)
{
    __shared__ unsigned short s_W[2][128 * 64];   // 2 x 16 KB
    __shared__ unsigned short s_S[2][64 * 64];    // 2 x  8 KB

    const int tid = threadIdx.x;
    const int bid = blockIdx.x;                 // 512 blocks = 2/CU
    // pair (bid, bid+256) = the two out-halves of one (b,h): same XCD,
    // typically same CU -> shared gather lines in L1/L2.
    const int ohalf = bid >> 8;
    const int r     = bid & 255;
    const int xcd   = r & 7;
    const int b     = xcd >> 1;
    const int h     = (xcd & 1) * 32 + (r >> 3);

    // sampling mapping: 8 threads per pixel, 8 channels (16B) each
    const int sp = tid >> 3;          // pixel 0..63
    const int c8 = tid & 7;           // 8-ch chunk 0..7

    const float yv0 = y[((b * 2 + 0) * H_ + h) * W_ + sp];
    const float yv1 = y[((b * 2 + 1) * H_ + h) * W_ + sp];
    const float spf = (float)(sp - 1 + PADO);       // x base (pre-padded)
    const float hpf = (float)(h  - 1 + PADO);       // y base (pre-padded)

    // mfma mapping: 8 waves = (oh 0..3) x (pg 0..1); wave = 32 outs x 32 px
    const int lane = tid & 63, wave = tid >> 6;
    const int pg  = wave & 1, oh = wave >> 1;       // oh 0..3
    const int l15 = lane & 15, kq = lane >> 4, sw = l15 & 7;

    f32x4 acc[4];   // [nt][mt] : 2 px-subtiles x 2 out-subtiles
    #pragma unroll
    for (int i = 0; i < 4; ++i) acc[i] = (f32x4){0.f, 0.f, 0.f, 0.f};

    const unsigned short* xb = xTp + (size_t)b * (PH * PW * 256) + c8 * 8;

    // single in-flight sample slot: ISSUE(t+1) at step top, WRITE(t+1) at
    // step bottom -- registers live across exactly one MFMA cluster.
    float wgt[4];
    uint4 gA, gB, gC, gD;

#define ISSUE_ONE(t) do {                                                      \
    const int t_ = (t);                                                        \
    const int g_ = t_ / 9, kk_ = t_ - g_ * 9;                                  \
    const float4 co = *(const float4*)(w_off + t_ * 4);                        \
    const float dy = fmaf(yv0, co.x, yv1 * co.y);                              \
    const float dx = fmaf(yv0, co.z, yv1 * co.w);                              \
    const float yc = hpf + (float)(kk_ / 3) + dy;                              \
    const float xc = spf + (float)(kk_ % 3) + dx;                              \
    const float yf = floorf(yc), xf = floorf(xc);                              \
    const float wy = yc - yf, wx = xc - xf;                                    \
    const int   yi = (int)yf, xi = (int)xf;     /* padded coords, >= 0 */      \
    const float omy = 1.f - wy, omx = 1.f - wx;                                \
    wgt[0] = omy * omx; wgt[1] = omy * wx;                                     \
    wgt[2] = wy * omx;  wgt[3] = wy * wx;                                      \
    const unsigned short* p0 = xb + (yi * PW + xi) * 256 + g_ * 64;            \
    const unsigned short* p1 = p0 + PW * 256;                                  \
    gA = *(const uint4*)(p0);        gB = *(const uint4*)(p0 + 256);           \
    gC = *(const uint4*)(p1);        gD = *(const uint4*)(p1 + 256);           \
} while (0)

// stage this block's 128-out half of wb tile t (16 KB) into s_W[buf]
#define STAGE_W(t, buf) do {                                                   \
    const unsigned short* src = wb + (size_t)(t) * 16384 + ohalf * 8192;       \
    _Pragma("unroll")                                                          \
    for (int j = 0; j < 2; ++j) {                                              \
        const int off = (j * 512 + tid) * 8;                                   \
        __builtin_amdgcn_global_load_lds((gptr_t)(src + off),                  \
                                         (lptr_t)(&s_W[buf][0] + off),         \
                                         16, 0, 0);                            \
    }                                                                          \
} while (0)

#define WRITE_ONE(SB) do {                                                     \
    const unsigned int av[4] = {gA.x, gA.y, gA.z, gA.w};                       \
    const unsigned int bv[4] = {gB.x, gB.y, gB.z, gB.w};                       \
    const unsigned int cv[4] = {gC.x, gC.y, gC.z, gC.w};                       \
    const unsigned int dv[4] = {gD.x, gD.y, gD.z, gD.w};                       \
    unsigned int res[4];                                                       \
    _Pragma("unroll")                                                          \
    for (int q = 0; q < 4; ++q) {                                              \
        float rl = wgt[0] * f_lo(av[q]);                                       \
        rl = fmaf(wgt[1], f_lo(bv[q]), rl);                                    \
        rl = fmaf(wgt[2], f_lo(cv[q]), rl);                                    \
        rl = fmaf(wgt[3], f_lo(dv[q]), rl);                                    \
        float rh = wgt[0] * f_hi(av[q]);                                       \
        rh = fmaf(wgt[1], f_hi(bv[q]), rh);                                    \
        rh = fmaf(wgt[2], f_hi(cv[q]), rh);                                    \
        rh = fmaf(wgt[3], f_hi(dv[q]), rh);                                    \
        res[q] = __builtin_amdgcn_perm(__float_as_uint(rh),                    \
                                       __float_as_uint(rl), 0x07060302u);      \
    }                                                                          \
    *(uint4*)(&s_S[SB][0] + sp * 64 + ((c8 ^ (sp & 7)) * 8)) =                 \
        make_uint4(res[0], res[1], res[2], res[3]);                            \
} while (0)

// one K=64 MFMA block: 8 ds_read_b128 + 8 MFMA (wave = 32 outs x 32 px)
#define MFMA_TAP(WB, SB) do {                                                  \
    bf16x8 bf[2][2], af[2][2];                                                 \
    _Pragma("unroll")                                                          \
    for (int kh = 0; kh < 2; ++kh) {                                           \
        const int pos = ((kh * 4 + kq) ^ sw) * 8;                              \
        _Pragma("unroll")                                                      \
        for (int nt = 0; nt < 2; ++nt)                                         \
            bf[kh][nt] = *(const bf16x8*)(&s_S[SB][0] +                        \
                              (pg * 32 + nt * 16 + l15) * 64 + pos);           \
        _Pragma("unroll")                                                      \
        for (int mt = 0; mt < 2; ++mt)                                         \
            af[kh][mt] = *(const bf16x8*)(&s_W[WB][0] +                        \
                              (oh * 32 + mt * 16 + l15) * 64 + pos);           \
    }                                                                          \
    __builtin_amdgcn_s_setprio(1);                                             \
    _Pragma("unroll")                                                          \
    for (int kh = 0; kh < 2; ++kh)                                             \
        _Pragma("unroll")                                                      \
        for (int nt = 0; nt < 2; ++nt)                                         \
            _Pragma("unroll")                                                  \
            for (int mt = 0; mt < 2; ++mt)                                     \
                acc[nt * 2 + mt] = __builtin_amdgcn_mfma_f32_16x16x32_bf16(    \
                    af[kh][mt], bf[kh][nt], acc[nt * 2 + mt], 0, 0, 0);        \
    __builtin_amdgcn_s_setprio(0);                                             \
} while (0)

    // ---- prologue: gather+stage step 0, write S[0], sync ----
    ISSUE_ONE(0);
    STAGE_W(0, 0);
    WRITE_ONE(0);                    // compiler-waits the gathers
    __syncthreads();                 // drains DMA(0) + S-writes

    // ---- main loop: steps 0..33 (buf = t&1 static), then 34, then 35 ----
    for (int t = 0; t < 34; t += 2) {
        ISSUE_ONE(t + 1);
        STAGE_W(t + 1, 1);
        MFMA_TAP(0, 0);
        WRITE_ONE(1);
        __syncthreads();

        ISSUE_ONE(t + 2);
        STAGE_W(t + 2, 0);
        MFMA_TAP(1, 1);
        WRITE_ONE(0);
        __syncthreads();
    }
    // step 34: prefetch 35, compute buf0
    ISSUE_ONE(35);
    STAGE_W(35, 1);
    MFMA_TAP(0, 0);
    WRITE_ONE(1);
    __syncthreads();
    // step 35: compute buf1, no prefetch, no trailing barrier
    MFMA_TAP(1, 1);

    // ---- epilogue: fused relu, direct final store. C/D: col->px, row->o ----
    #pragma unroll
    for (int nt = 0; nt < 2; ++nt) {
        const int px = pg * 32 + nt * 16 + l15;
        #pragma unroll
        for (int mt = 0; mt < 2; ++mt) {
            const int obase = ohalf * 128 + oh * 32 + mt * 16 + kq * 4;
            #pragma unroll
            for (int rr = 0; rr < 4; ++rr) {
                out[(((size_t)b * COUT_ + obase + rr) * H_ + h) * W_ + px] =
                    fmaxf(acc[nt * 2 + mt][rr], 0.f);
            }
        }
    }
#undef ISSUE_ONE
#undef STAGE_W
#undef WRITE_ONE
#undef MFMA_TAP
}

extern "C" void kernel_launch(void* const* d_in, const int* in_sizes, int n_in,
                              void* d_out, int out_size, void* d_ws, size_t ws_size,
                              hipStream_t stream) {
    const float* x     = (const float*)d_in[0];
    const float* y     = (const float*)d_in[1];
    const float* w_off = (const float*)d_in[2];
    const float* w_def = (const float*)d_in[3];
    float* out = (float*)d_out;

    unsigned short* xTp = (unsigned short*)d_ws;            // 4*80*80*256*2B = 13.1 MB
    unsigned short* wb  = (unsigned short*)d_ws + (size_t)B_ * PH * PW * 256;  // 1.18 MB

    prep_kernel<<<2880, 256, 0, stream>>>(x, xTp, w_def, wb);
    dcn_kernel<<<512, 512, 0, stream>>>(xTp, y, w_off, wb, out);
}

// Round 12
// 117.231 us; speedup vs baseline: 1.0222x; 1.0222x over previous
//
#include <hip/hip_runtime.h>
#include <cstddef>

#define B_    4
#define CIN_  256
#define COUT_ 256
#define H_    64
#define W_    64
#define KK_   9
#define G_    4
#define PW    80          // padded row width  (pad 8 each side)
#define PH    80          // padded rows
#define PADO  8           // pad offset

typedef short bf16x8 __attribute__((ext_vector_type(8)));
typedef float f32x4  __attribute__((ext_vector_type(4)));
typedef __attribute__((address_space(1))) const unsigned int* gptr_t;
typedef __attribute__((address_space(3))) unsigned int*       lptr_t;

__device__ __forceinline__ unsigned short f2bf(float v) {
    unsigned int u = __float_as_uint(v);
    u += 0x7fffu + ((u >> 16) & 1u);
    return (unsigned short)(u >> 16);
}
__device__ __forceinline__ float f_lo(unsigned int u) { return __uint_as_float(u << 16); }
__device__ __forceinline__ float f_hi(unsigned int u) { return __uint_as_float(u & 0xffff0000u); }

// Merged prep:
//   blocks [0,512):    xTp interior rows (x-borders zeroed inline)
//   blocks [512,576):  xTp border rows zero-fill
//   blocks [576,2880): wb weight repack (36 tiles, pos-swizzled)
__global__ __launch_bounds__(256) void prep_kernel(const float* __restrict__ x,
                                                   unsigned short* __restrict__ xTp,
                                                   const float* __restrict__ w,
                                                   unsigned short* __restrict__ wb) {
    const int tid = threadIdx.x;
    if (blockIdx.x < 512) {
        __shared__ unsigned short s[128][66];
        const int bh    = blockIdx.x >> 1;
        const int chalf = blockIdx.x & 1;
        const int b     = bh >> 6, h = bh & 63;
        const size_t src_base = ((size_t)b * CIN_ + chalf * 128) * (H_ * W_) + h * W_;
        #pragma unroll 4
        for (int k = 0; k < 32; ++k) {
            int i = k * 256 + tid;
            int c = i >> 6, ww = i & 63;
            s[c][ww] = f2bf(x[src_base + (size_t)c * (H_ * W_) + ww]);
        }
        __syncthreads();
        const size_t dst_row = ((size_t)b * PH + (h + PADO)) * PW;
        #pragma unroll 4
        for (int k = 0; k < 20; ++k) {              // 80 w' x 64 ch-pairs
            int j  = k * 256 + tid;
            int c2 = (j & 63) * 2, wp = j >> 6;     // wp in [0,80)
            unsigned int v = 0;
            if (wp >= PADO && wp < PADO + W_) {
                int ww = wp - PADO;
                v = (unsigned int)s[c2][ww] | ((unsigned int)s[c2 + 1][ww] << 16);
            }
            *(unsigned int*)(xTp + (dst_row + wp) * 256 + chalf * 128 + c2) = v;
        }
    } else if (blockIdx.x < 576) {
        const int bidx = blockIdx.x - 512;          // [0,64)
        const int b = bidx >> 4, rr = bidx & 15;
        const int yp = (rr < PADO) ? rr : (PH - 16 + rr);   // 0..7 or 72..79
        unsigned short* dst = xTp + ((size_t)b * PH + yp) * PW * 256;
        #pragma unroll
        for (int k = 0; k < 10; ++k) {              // 80*256 shorts = 2560 x 16B
            *(uint4*)(dst + (size_t)(k * 256 + tid) * 8) = make_uint4(0, 0, 0, 0);
        }
    } else {
        int idx = (blockIdx.x - 576) * 256 + tid;   // 36*16384 exactly
        int e   = idx & 7;
        int pos = (idx >> 3) & 7;
        int o   = (idx >> 6) & 255;
        int t   = idx >> 14;                        // g*9 + kk
        int g   = t / 9, kk = t - g * 9;
        int j   = pos ^ (o & 7);
        int c   = g * 64 + j * 8 + e;
        wb[idx] = f2bf(w[(o * CIN_ + c) * KK_ + kk]);
    }
}

// Main kernel (session best, round 10): tap-pair structure (K=128 per
// barrier-step), unpinned schedule -- the compiler inserts exact counted
// waits and its schedule measured identical to hand-pinned (r10 == r7).
// 256 blocks x 512 threads, 1/CU, LDS 160 KB. One __syncthreads per pair.
__global__ __launch_bounds__(512, 2) void dcn_kernel(
    const unsigned short* __restrict__ xTp, const float* __restrict__ y,
    const float* __restrict__ w_off, const unsigned short* __restrict__ wb,
    float* __restrict__ out)
{
    __shared__ unsigned short s_W[2][2][16384];   // [buf][tap-half][256o*64c] 128 KB
    __shared__ unsigned short s_S[2][2][4096];    // [buf][tap-half][64px*64c]  32 KB

    const int tid = threadIdx.x;
    const int bid = blockIdx.x;                 // 256 blocks = 1/CU
    const int xcd = bid & 7;
    const int b   = xcd >> 1;
    const int h   = (xcd & 1) * 32 + (bid >> 3);

    // sampling mapping: 8 threads per pixel, 8 channels (16B) each
    const int sp = tid >> 3;          // pixel 0..63
    const int c8 = tid & 7;           // 8-ch chunk 0..7

    const float yv0 = y[((b * 2 + 0) * H_ + h) * W_ + sp];
    const float yv1 = y[((b * 2 + 1) * H_ + h) * W_ + sp];
    const float spf = (float)(sp - 1 + PADO);       // x base (pre-padded)
    const float hpf = (float)(h  - 1 + PADO);       // y base (pre-padded)

    // mfma mapping: 8 waves, wave = 64 outs (oh) x 32 px (pg)
    const int lane = tid & 63, wave = tid >> 6;
    const int pg  = wave & 1, oh = wave >> 1;       // oh 0..3
    const int l15 = lane & 15, kq = lane >> 4, sw = l15 & 7;

    f32x4 acc[8];   // [nt][mt] : 2 px-subtiles x 4 out-subtiles
    #pragma unroll
    for (int i = 0; i < 8; ++i) acc[i] = (f32x4){0.f, 0.f, 0.f, 0.f};

    const unsigned short* xb = xTp + (size_t)b * (PH * PW * 256) + c8 * 8;

    // two tap slots in flight (all indices compile-time -- rule #20)
    float wgt[2][4];
    uint4 gA[2], gB[2], gC[2], gD[2];

#define ISSUE_ONE(t, P) do {                                                   \
    const int t_ = (t);                                                        \
    const int g_ = t_ / 9, kk_ = t_ - g_ * 9;                                  \
    const float4 co = *(const float4*)(w_off + t_ * 4);                        \
    const float dy = fmaf(yv0, co.x, yv1 * co.y);                              \
    const float dx = fmaf(yv0, co.z, yv1 * co.w);                              \
    const float yc = hpf + (float)(kk_ / 3) + dy;                              \
    const float xc = spf + (float)(kk_ % 3) + dx;                              \
    const float yf = floorf(yc), xf = floorf(xc);                              \
    const float wy = yc - yf, wx = xc - xf;                                    \
    const int   yi = (int)yf, xi = (int)xf;     /* padded coords, >= 0 */      \
    const float omy = 1.f - wy, omx = 1.f - wx;                                \
    wgt[P][0] = omy * omx; wgt[P][1] = omy * wx;                               \
    wgt[P][2] = wy * omx;  wgt[P][3] = wy * wx;                                \
    const unsigned short* p0 = xb + (yi * PW + xi) * 256 + g_ * 64;            \
    const unsigned short* p1 = p0 + PW * 256;                                  \
    gA[P] = *(const uint4*)(p0);        gB[P] = *(const uint4*)(p0 + 256);     \
    gC[P] = *(const uint4*)(p1);        gD[P] = *(const uint4*)(p1 + 256);     \
} while (0)

// stage one PAIR (2 consecutive wb tiles = 64 KB) into s_W[buf]
#define STAGE_W2(t, buf) do {                                                  \
    const unsigned short* src = wb + (size_t)(t) * 32768;                      \
    _Pragma("unroll")                                                          \
    for (int j = 0; j < 8; ++j) {                                              \
        const int off = (j * 512 + tid) * 8;                                   \
        __builtin_amdgcn_global_load_lds((gptr_t)(src + off),                  \
                                         (lptr_t)(&s_W[buf][0][0] + off),      \
                                         16, 0, 0);                            \
    }                                                                          \
} while (0)

#define WRITE_ONE(P, SB) do {                                                  \
    const unsigned int av[4] = {gA[P].x, gA[P].y, gA[P].z, gA[P].w};           \
    const unsigned int bv[4] = {gB[P].x, gB[P].y, gB[P].z, gB[P].w};           \
    const unsigned int cv[4] = {gC[P].x, gC[P].y, gC[P].z, gC[P].w};           \
    const unsigned int dv[4] = {gD[P].x, gD[P].y, gD[P].z, gD[P].w};           \
    unsigned int res[4];                                                       \
    _Pragma("unroll")                                                          \
    for (int q = 0; q < 4; ++q) {                                              \
        float rl = wgt[P][0] * f_lo(av[q]);                                    \
        rl = fmaf(wgt[P][1], f_lo(bv[q]), rl);                                 \
        rl = fmaf(wgt[P][2], f_lo(cv[q]), rl);                                 \
        rl = fmaf(wgt[P][3], f_lo(dv[q]), rl);                                 \
        float rh = wgt[P][0] * f_hi(av[q]);                                    \
        rh = fmaf(wgt[P][1], f_hi(bv[q]), rh);                                 \
        rh = fmaf(wgt[P][2], f_hi(cv[q]), rh);                                 \
        rh = fmaf(wgt[P][3], f_hi(dv[q]), rh);                                 \
        res[q] = __builtin_amdgcn_perm(__float_as_uint(rh),                    \
                                       __float_as_uint(rl), 0x07060302u);      \
    }                                                                          \
    *(uint4*)(&s_S[SB][P][0] + sp * 64 + ((c8 ^ (sp & 7)) * 8)) =              \
        make_uint4(res[0], res[1], res[2], res[3]);                            \
} while (0)

// one K=64 MFMA block: W buf WB, tap-half HF, S buf SB (r2-proven layout)
#define MFMA_TAP(WB, HF, SB) do {                                              \
    bf16x8 bf[2][2], af[2][4];                                                 \
    _Pragma("unroll")                                                          \
    for (int kh = 0; kh < 2; ++kh) {                                           \
        const int pos = ((kh * 4 + kq) ^ sw) * 8;                              \
        _Pragma("unroll")                                                      \
        for (int nt = 0; nt < 2; ++nt)                                         \
            bf[kh][nt] = *(const bf16x8*)(&s_S[SB][HF][0] +                    \
                              (pg * 32 + nt * 16 + l15) * 64 + pos);           \
        _Pragma("unroll")                                                      \
        for (int mt = 0; mt < 4; ++mt)                                         \
            af[kh][mt] = *(const bf16x8*)(&s_W[WB][HF][0] +                    \
                              (oh * 64 + mt * 16 + l15) * 64 + pos);           \
    }                                                                          \
    __builtin_amdgcn_s_setprio(1);                                             \
    _Pragma("unroll")                                                          \
    for (int kh = 0; kh < 2; ++kh)                                             \
        _Pragma("unroll")                                                      \
        for (int nt = 0; nt < 2; ++nt)                                         \
            _Pragma("unroll")                                                  \
            for (int mt = 0; mt < 4; ++mt)                                     \
                acc[nt * 4 + mt] = __builtin_amdgcn_mfma_f32_16x16x32_bf16(    \
                    af[kh][mt], bf[kh][nt], acc[nt * 4 + mt], 0, 0, 0);        \
    __builtin_amdgcn_s_setprio(0);                                             \
} while (0)

// Pair-step s (P = s&1). NO scheduling pins: the gather->bilinear->ds_write
// chain (pair s+1) and the ds_read->MFMA chain (pair s) are independent;
// the compiler interleaves them and inserts exact counted waits. The single
// __syncthreads drains DMA+ds_writes and flips the double buffer.
#define STEP(s_, P, DO_PF) do {                                                \
    if (DO_PF) { ISSUE_ONE(2 * (s_) + 2, 0); ISSUE_ONE(2 * (s_) + 3, 1); }     \
    if (DO_PF) STAGE_W2((s_) + 1, P ^ 1);                                      \
    MFMA_TAP(P, 0, P);                                                         \
    if (DO_PF) WRITE_ONE(0, P ^ 1);                                            \
    MFMA_TAP(P, 1, P);                                                         \
    if (DO_PF) WRITE_ONE(1, P ^ 1);                                            \
    __syncthreads();                                                           \
} while (0)

    // ---- prologue: gather+stage pair 0, write S[0], sync ----
    ISSUE_ONE(0, 0);
    ISSUE_ONE(1, 1);
    STAGE_W2(0, 0);
    WRITE_ONE(0, 0);
    WRITE_ONE(1, 0);
    __syncthreads();

    // ---- main loop: pairs 0..15 (static buf indices), then 16, then 17 ----
    for (int sb = 0; sb < 16; sb += 2) {
        STEP(sb + 0, 0, 1);
        STEP(sb + 1, 1, 1);
    }
    STEP(16, 0, 1);                   // prefetches pair 17 -> buf1 / S[1]
    MFMA_TAP(1, 0, 1);                // pair 17, no barrier before epilogue
    MFMA_TAP(1, 1, 1);

    // ---- epilogue: fused relu, direct final store. C/D: col->px, row->o ----
    #pragma unroll
    for (int nt = 0; nt < 2; ++nt) {
        const int px = pg * 32 + nt * 16 + l15;
        #pragma unroll
        for (int mt = 0; mt < 4; ++mt) {
            const int obase = oh * 64 + mt * 16 + kq * 4;
            #pragma unroll
            for (int rr = 0; rr < 4; ++rr) {
                out[(((size_t)b * COUT_ + obase + rr) * H_ + h) * W_ + px] =
                    fmaxf(acc[nt * 4 + mt][rr], 0.f);
            }
        }
    }
#undef ISSUE_ONE
#undef STAGE_W2
#undef WRITE_ONE
#undef MFMA_TAP
#undef STEP
}

extern "C" void kernel_launch(void* const* d_in, const int* in_sizes, int n_in,
                              void* d_out, int out_size, void* d_ws, size_t ws_size,
                              hipStream_t stream) {
    const float* x     = (const float*)d_in[0];
    const float* y     = (const float*)d_in[1];
    const float* w_off = (const float*)d_in[2];
    const float* w_def = (const float*)d_in[3];
    float* out = (float*)d_out;

    unsigned short* xTp = (unsigned short*)d_ws;            // 4*80*80*256*2B = 13.1 MB
    unsigned short* wb  = (unsigned short*)d_ws + (size_t)B_ * PH * PW * 256;  // 1.18 MB

    prep_kernel<<<2880, 256, 0, stream>>>(x, xTp, w_def, wb);
    dcn_kernel<<<256, 512, 0, stream>>>(xTp, y, w_off, wb, out);
}